// Round 7
// baseline (7118.784 us; speedup 1.0000x reference)
//
#include <hip/hip_runtime.h>

// Problem constants
#define Bn 32
#define Tn 1024
#define Dn 512
#define Hn 512
#define Vn 64
#define Sn 128
#define NTS 8          // t-slices per batch
#define TT 128         // T per block (attention role)
#define NTHREADS 512
#define KIH 576        // W_ih cols (V + H)
#define NBLK 256

// LDS: 131072 (tile) + 15488 (scratch incl. wow_s[32][64]) = 146560 -> 147456
#define LDS_BYTES 147456
#define OUT_ATT ((size_t)Sn * Bn * Vn)

// ws u32-index layout, first 4KB (memset to 0 each launch):
//   [g*16 + 0]  : global-barrier arrival counter for group g (monotonic)
//   [g*16 + 4,5]: E->C group barrier (arrivals, gen) for group g
//   [512]       : dtype flag (probe)
// ws float-index layout:
#define WS_XCTX  1024     // [32][512]  ctx(s-1)
#define WS_XH    17408    // [2][32][512] h double-buffered by step parity
#define WS_LGP   50176    // [32][64][8] logits partials
#define WS_MST   66560    // [32][8]
#define WS_LST   66816    // [32][8]
#define WS_CTXP  67072    // [32][8][512]

struct F8 { float4 a, b; };

__device__ __forceinline__ float bfu(unsigned short u){ return __uint_as_float(((unsigned int)u)<<16); }
__device__ __forceinline__ float bflo(unsigned int u){ return __uint_as_float(u<<16); }
__device__ __forceinline__ float bfhi(unsigned int u){ return __uint_as_float(u & 0xffff0000u); }
__device__ __forceinline__ unsigned short f2bf(float f){
  unsigned int x = __float_as_uint(f);
  return (unsigned short)((x + 0x7fffu + ((x>>16)&1u)) >> 16);   // RNE
}
__device__ __forceinline__ F8 ld8(const unsigned short* p){
  uint4 q = *(const uint4*)p;
  F8 r;
  r.a = make_float4(bflo(q.x), bfhi(q.x), bflo(q.y), bfhi(q.y));
  r.b = make_float4(bflo(q.z), bfhi(q.z), bflo(q.w), bfhi(q.w));
  return r;
}
__device__ __forceinline__ F8 ld8(const float* p){
  F8 r; r.a = *(const float4*)p; r.b = *(const float4*)(p+4); return r;
}
__device__ __forceinline__ float dot8(F8 w, float4 a, float4 b){
  return w.a.x*a.x + w.a.y*a.y + w.a.z*a.z + w.a.w*a.w
       + w.b.x*b.x + w.b.y*b.y + w.b.z*b.z + w.b.w*b.w;
}
__device__ __forceinline__ float dot64g(const unsigned short* __restrict__ w, const float* x){
  const float4* x4 = (const float4*)x;
  float acc = 0.f;
#pragma unroll
  for(int i=0;i<8;i++) acc += dot8(ld8(w+8*i), x4[2*i], x4[2*i+1]);
  return acc;
}
__device__ __forceinline__ float sigm(float x){
  x = fminf(fmaxf(x, -30.f), 30.f); return 1.f/(1.f + expf(-x));
}
__device__ __forceinline__ float tnh(float x){
  return tanhf(fminf(fmaxf(x, -20.f), 20.f));
}

// Recursive-halving reduce-scatter (R6-verified): after rs32, lane pair
// {2i,2i+1} holds in a[0] the 64-lane sum of value index i (i in 0..31).
template<int N>
__device__ __forceinline__ void rs_round(float* a, int off, bool hi){
#pragma unroll
  for(int i=0;i<N;i++){
    float send = hi ? a[i]   : a[i+N];
    float keep = hi ? a[i+N] : a[i];
    float recv = __shfl_xor(send, off);
    a[i] = keep + recv;
  }
}
__device__ __forceinline__ void rs32(float* a, int lane){
  rs_round<16>(a, 32, (lane&32)!=0);
  rs_round< 8>(a, 16, (lane&16)!=0);
  rs_round< 4>(a,  8, (lane& 8)!=0);
  rs_round< 2>(a,  4, (lane& 4)!=0);
  rs_round< 1>(a,  2, (lane& 2)!=0);
  a[0] += __shfl_xor(a[0], 1);
}

// ---- relaxed agent-scope atomics (write-through to the coherence point) ----
__device__ __forceinline__ void aput(float* p, float v){
  __hip_atomic_store(p, v, __ATOMIC_RELAXED, __HIP_MEMORY_SCOPE_AGENT);
}
__device__ __forceinline__ float aget(const float* p){
  return __hip_atomic_load(p, __ATOMIC_RELAXED, __HIP_MEMORY_SCOPE_AGENT);
}
__device__ __forceinline__ unsigned int uget(const unsigned int* p){
  return __hip_atomic_load(p, __ATOMIC_RELAXED, __HIP_MEMORY_SCOPE_AGENT);
}

// ---- all-poll global barrier (R7) ----
// Arrivals distributed over 32 group lines (8 RMWs each, parallel). EVERY
// block's wave 0 gather-polls all 32 counters (reads only — no hot-line RMW
// serialization, no master/broadcast hops). Serial depth ~2 LLC round-trips.
// One ACQUIRE load at exit keeps subsequent plain loads coherent.
__device__ __forceinline__ void gbar2(unsigned int* wsu, unsigned int ggen){
  asm volatile("s_waitcnt vmcnt(0)" ::: "memory");
  __syncthreads();
  const int tid = threadIdx.x;
  const int grp = (int)blockIdx.x >> 3;
  if(tid == 0)
    __hip_atomic_fetch_add(&wsu[grp*16], 1u, __ATOMIC_RELEASE, __HIP_MEMORY_SCOPE_AGENT);
  if(tid < 64){
    const unsigned int tgt = 8u*ggen;
    for(;;){
      unsigned int v = (tid < 32) ? uget(&wsu[tid*16]) : tgt;
      if(__all(v >= tgt)) break;
      __builtin_amdgcn_s_sleep(1);
    }
    if(tid == 0){
      unsigned int x = __hip_atomic_load(&wsu[grp*16], __ATOMIC_ACQUIRE, __HIP_MEMORY_SCOPE_AGENT);
      asm volatile("" :: "v"(x));
    }
  }
  __syncthreads();
  asm volatile("" ::: "memory");
}

// ---- 8-block group barrier (E->C; partials are group-local) — R1-proven ----
__device__ __forceinline__ void gbarE(unsigned int* line){
  asm volatile("s_waitcnt vmcnt(0)" ::: "memory");
  __syncthreads();
  if(threadIdx.x == 0){
    unsigned int g = uget(line+1);
    unsigned int p = __hip_atomic_fetch_add(line, 1u, __ATOMIC_RELEASE, __HIP_MEMORY_SCOPE_AGENT);
    if(p == g*8u + 7u){
      __hip_atomic_store(line+1, g+1u, __ATOMIC_RELEASE, __HIP_MEMORY_SCOPE_AGENT);
    } else {
      while(uget(line+1) == g) __builtin_amdgcn_s_sleep(1);
    }
    unsigned int x = __hip_atomic_load(line+1, __ATOMIC_ACQUIRE, __HIP_MEMORY_SCOPE_AGENT);
    asm volatile("" :: "v"(x));
  }
  __syncthreads();
  asm volatile("" ::: "memory");
}

// dtype probe: b_ih ~ N(0,0.01^2). flag: 1 = bf16, 2 = f32.
__global__ void dtype_probe(const unsigned short* __restrict__ b3, unsigned int* flag){
  const int t = threadIdx.x;
  bool ok = true;
#pragma unroll
  for(int i=0;i<8;i++){
    float v = bfu(b3[2*(t*8+i)]);
    ok = ok && (v == v) && (fabsf(v) < 0.5f);
  }
  unsigned long long m = __ballot(ok);
  if(t == 0)
    __hip_atomic_store(flag, (m == ~0ull) ? 1u : 2u, __ATOMIC_RELEASE, __HIP_MEMORY_SCOPE_AGENT);
}

// ============================================================================
// v6 (f32 inputs): gates repartitioned to (8 units x 8 batches)/block:
//   ug = UP>>2 (unit octet), bg = UP&3 (batch octet). 32 gate-rows/block,
//   4 rows/wave, 64 weight VGPRs/lane. x-reads: 256KB issued / 32KB unique
//   per block-step (was 1MB / 128KB). Attention role unchanged (b_att=UP>>3,
//   ts=UP&7). All-poll global barrier. rs32 reductions (R6).
// ============================================================================
__global__ __launch_bounds__(NTHREADS, 1)
void speller_v3(const float* __restrict__ lf,  const float* __restrict__ wih,
                const float* __restrict__ whh, const float* __restrict__ bih,
                const float* __restrict__ bhh, const float* __restrict__ wout,
                const float* __restrict__ bout, float* __restrict__ out,
                float* __restrict__ ws)
{
  { unsigned int fl = __hip_atomic_load((unsigned int*)ws + 512, __ATOMIC_ACQUIRE, __HIP_MEMORY_SCOPE_AGENT);
    if(fl != 2u) return; }

  const int tid   = threadIdx.x;
  const int UP    = (int)blockIdx.x;
  const int b_att = UP >> 3;              // attention batch
  const int ts    = UP & 7;               // attention t-slice
  const int ug    = UP >> 2;              // gates: unit octet (units ug*8..+7)
  const int bg    = UP & 3;               // gates: batch octet (bb bg*8..+7)
  const int w     = tid >> 6;             // wave 0..7
  const int lane  = tid & 63;

  extern __shared__ char smem[];
  float* tile   = (float*)smem;                 // [64][512] f32 swizzled LF rows 0..63
  float* epart  = (float*)(smem + 131072);      // [512]
  float* h_s    = epart + 512;                  // [512]
  float* e_s    = h_s + 512;                    // [128]
  float* p_s    = e_s + 128;                    // [128]
  float* red_s  = p_s + 128;                    // [32]
  float* pre_s  = red_s + 32;                   // [32 rows][8 bb]
  float* ctxc_s = pre_s + 256;                  // [64]
  float* c_s    = ctxc_s + 64;                  // [64] cell state (bb_loc*8+u_loc)
  float* bias_s = c_s + 64;                     // [32 rows]
  float* bout_s = bias_s + 32;                  // [64]
  int*   pall_s = (int*)(bout_s + 64);          // [32] argmax per batch
  float* wow_s  = (float*)(pall_s + 32);        // [32 rows][64] W_ih one-hot cols
  // end of scratch = 131072 + 15488 = 146560 <= LDS_BYTES

  unsigned int* wsu   = (unsigned int*)ws;
  unsigned int* eline = wsu + (size_t)b_att*16 + 4;
  float* xctx = ws + WS_XCTX;
  float* xh   = ws + WS_XH;
  float* lgp  = ws + WS_LGP;
  float* mst  = ws + WS_MST;
  float* lst  = ws + WS_LST;
  float* ctxp = ws + WS_CTXP;

  // ---- persistent weight registers: 4 rows/wave x 16 floats/lane ----
  // row_loc = 4w+r in [0,32); gate = row_loc>>3; unit = ug*8 + (row_loc&7)
  float4 wv[4][4];
  {
#pragma unroll
    for(int r=0;r<4;++r){
      const int row_loc = 4*w + r;
      const int grow = (row_loc>>3)*Hn + ug*8 + (row_loc&7);
      const float* wp = (lane < 32) ? (wih + (size_t)grow*KIH + 64 + 16*lane)
                                    : (whh + (size_t)grow*Hn + (16*lane - 512));
      wv[r][0] = ((const float4*)wp)[0];
      wv[r][1] = ((const float4*)wp)[1];
      wv[r][2] = ((const float4*)wp)[2];
      wv[r][3] = ((const float4*)wp)[3];
    }
  }
  float4 oh0, oh1, oc0, oc1;      // W_out K-slice (attention role)
  {
    const int v = tid>>3, q = tid&7;
    const float* pH = wout + (size_t)v*(2*Hn) + ts*64 + q*8;
    const float* pC = pH + Hn;
    oh0 = *(const float4*)pH; oh1 = *(const float4*)(pH+4);
    oc0 = *(const float4*)pC; oc1 = *(const float4*)(pC+4);
  }

  // ---- LDS weight/aux fills ----
#pragma unroll
  for(int i=0;i<4;i++){   // wow_s[32][64]
    const int idx = tid + i*NTHREADS;
    const int row_loc = idx >> 6, cc = idx & 63;
    const int grow = (row_loc>>3)*Hn + ug*8 + (row_loc&7);
    wow_s[idx] = wih[(size_t)grow*KIH + cc];
  }
  if(tid < 32){
    const int grow = (tid>>3)*Hn + ug*8 + (tid&7);
    bias_s[tid] = bih[grow] + bhh[grow];
  }
  if(tid < Vn) bout_s[tid] = bout[tid];
  if(tid < 64) c_s[tid] = 0.f;
  if(tid < 32) pall_s[tid] = 0;

  // ---- LF staging: rows 0..63 -> swizzled LDS; rows 64..127 -> registers ----
  float lfreg[64];
  {
    const float4* s4 = (const float4*)(lf + ((size_t)b_att*Tn + (size_t)ts*TT) * Dn);
    float4* d4 = (float4*)tile;
#pragma unroll
    for(int i=0;i<16;i++){
      const int f = tid + i*NTHREADS;       // float4 index in [0,8192)
      const int row = f >> 7, cc = f & 127;
      d4[(row << 7) | (cc ^ (row & 7))] = s4[f];
    }
    const float* lfg = lf + ((size_t)b_att*Tn + (size_t)ts*TT + 64) * Dn + tid;
#pragma unroll
    for(int j=0;j<64;j++) lfreg[j] = lfg[(size_t)j*Dn];
  }

  // ---- ws init: ctx(-1) = LF[:,0,:]; own h(-1) states = 0 (parity 1) ----
  if(tid < 64){
    aput(&xctx[(size_t)b_att*Dn + ts*64 + tid], lf[(size_t)b_att*Tn*Dn + ts*64 + tid]);
    const int bb = bg*8 + (tid>>3), u = ug*8 + (tid&7);
    aput(&xh[(size_t)Bn*Hn + (size_t)bb*Hn + u], 0.f);
  }
  __syncthreads();
  unsigned int gg = 0;
  gbar2(wsu, ++gg);

  for(int s = 0; s <= Sn; ++s){
    // ================= G phase =================
    if(s > 0){   // logits(s-1) assembly + argmax (all blocks) + logp (writer blocks)
      for(int ii=0; ii<4; ++ii){
        const int bb = 4*w + ii;
        float lv = bout_s[lane];
        const float4* lp = (const float4*)(lgp + ((size_t)bb*Vn + lane)*8);
        float4 qa = lp[0], qb = lp[1];
        lv += qa.x+qa.y+qa.z+qa.w + qb.x+qb.y+qb.z+qb.w;
        float mv = lv; int mi = lane;
#pragma unroll
        for(int off=1; off<64; off<<=1){
          float ov = __shfl_xor(mv, off);
          int   oi = __shfl_xor(mi, off);
          if(ov > mv || (ov == mv && oi < mi)){ mv = ov; mi = oi; }
        }
        float se = expf(lv - mv);
#pragma unroll
        for(int off=1; off<64; off<<=1) se += __shfl_xor(se, off);
        if(lane == 0) pall_s[bb] = mi;
        if(UP == 8*bb) out[((size_t)(s-1)*Bn + bb)*Vn + lane] = lv - mv - logf(se);
      }
    }
    if(s == Sn) break;
    __syncthreads();   // pall_s ready

    // gates GEMV: 4 rows/wave x 8 batches; lane = 16-dim K chunk.
    {
      const float* xhR = xh + (size_t)(((s+1)&1))*Bn*Hn;   // h(s-1)
      const int k0 = 16*lane;
      const float* xbase = (lane < 32) ? (xctx + (size_t)(bg*8)*Dn + k0)
                                       : (xhR  + (size_t)(bg*8)*Hn + (k0 - 512));
      float acc[32];
#pragma unroll
      for(int bb=0; bb<8; ++bb){
        const float4* xp = (const float4*)(xbase + (size_t)bb*512);
        float4 x0 = xp[0], x1 = xp[1], x2 = xp[2], x3 = xp[3];
#pragma unroll
        for(int r=0;r<4;++r){
          acc[r*8+bb] = wv[r][0].x*x0.x + wv[r][0].y*x0.y + wv[r][0].z*x0.z + wv[r][0].w*x0.w
                      + wv[r][1].x*x1.x + wv[r][1].y*x1.y + wv[r][1].z*x1.z + wv[r][1].w*x1.w
                      + wv[r][2].x*x2.x + wv[r][2].y*x2.y + wv[r][2].z*x2.z + wv[r][2].w*x2.w
                      + wv[r][3].x*x3.x + wv[r][3].y*x3.y + wv[r][3].z*x3.z + wv[r][3].w*x3.w;
        }
      }
      rs32(acc, lane);
      if((lane & 1) == 0){
        const int i = lane>>1;                 // value index: r = i>>3, bb = i&7
        pre_s[(w*4 + (i>>3))*8 + (i&7)] = acc[0];
      }
    }
    __syncthreads();
    if(tid < 64){   // c,h update: 8 units x 8 batches
      const int bb_loc = tid>>3, u_loc = tid&7;
      const int bb = bg*8 + bb_loc;
      const int pidx = pall_s[bb];
      float gi = sigm(pre_s[(0*8+u_loc)*8+bb_loc] + wow_s[(0*8+u_loc)*64+pidx] + bias_s[0*8+u_loc]);
      float gf = sigm(pre_s[(1*8+u_loc)*8+bb_loc] + wow_s[(1*8+u_loc)*64+pidx] + bias_s[1*8+u_loc]);
      float gg2 = tnh(pre_s[(2*8+u_loc)*8+bb_loc] + wow_s[(2*8+u_loc)*64+pidx] + bias_s[2*8+u_loc]);
      float go = sigm(pre_s[(3*8+u_loc)*8+bb_loc] + wow_s[(3*8+u_loc)*64+pidx] + bias_s[3*8+u_loc]);
      float c = gf*c_s[tid] + gi*gg2;
      c_s[tid] = c;
      aput(&xh[(size_t)(s&1)*Bn*Hn + (size_t)bb*Hn + ug*8 + u_loc], go*tnh(c));
    }
    gbar2(wsu, ++gg);

    // ================= E phase (attention) =================
    h_s[tid] = xh[(size_t)(s&1)*Bn*Hn + (size_t)b_att*Hn + tid];
    __syncthreads();
    {  // rows 0..63: one row per thread-group from swizzled tile
      const int t1 = tid >> 3, q = tid & 7, mm = t1 & 7;
      const float4* lrow = (const float4*)tile + (size_t)t1*128;
      const float4* hq = (const float4*)(h_s + q*64);
      float ea = 0.f;
#pragma unroll
      for(int i=0;i<8;i++){
        const int c0 = q*16 + 2*i;
        F8 wvv; wvv.a = lrow[c0 ^ mm]; wvv.b = lrow[(c0+1) ^ mm];
        ea += dot8(wvv, hq[2*i], hq[2*i+1]);
      }
#pragma unroll
      for(int off=1; off<8; off<<=1) ea += __shfl_xor(ea, off);
      if(q==0) e_s[t1] = ea;
    }
    {  // rows 64..127: reduce-scatter over register columns, two 32-row halves
      const float h_own = h_s[tid];
      float a[32];
#pragma unroll
      for(int j=0;j<32;j++) a[j] = h_own * lfreg[j];
      rs32(a, lane);
      if((lane & 1) == 0) epart[(w<<6) + (lane>>1)] = a[0];
#pragma unroll
      for(int j=0;j<32;j++) a[j] = h_own * lfreg[32+j];
      rs32(a, lane);
      if((lane & 1) == 0) epart[(w<<6) + 32 + (lane>>1)] = a[0];
    }
    __syncthreads();
    if(tid < 64){
      float s2 = 0.f;
#pragma unroll
      for(int w2=0; w2<8; w2++) s2 += epart[(w2<<6) + tid];
      e_s[64 + tid] = s2;
      float v = fmaxf(e_s[tid], s2);
#pragma unroll
      for(int off=1; off<64; off<<=1) v = fmaxf(v, __shfl_xor(v,off));
      if(tid==0) red_s[10] = v;
    }
    __syncthreads();
    if(tid < TT) p_s[tid] = expf(e_s[tid] - red_s[10]);
    __syncthreads();
    if(tid < 64){
      float v = p_s[tid] + p_s[tid+64];
#pragma unroll
      for(int off=1; off<64; off<<=1) v += __shfl_xor(v,off);
      if(tid==0){
        aput(&mst[(size_t)b_att*NTS + ts], red_s[10]);
        aput(&lst[(size_t)b_att*NTS + ts], v);
      }
    }
    {  // ctx partial: thread owns one d, sweep 128 t's
      float acc = 0.f;
      const int cs = tid >> 2, cr = tid & 3;
#pragma unroll
      for(int t=0;t<64;t++)
        acc += p_s[t] * tile[(size_t)t*Dn + (((cs ^ (t&7))<<2) | cr)];
#pragma unroll
      for(int j=0;j<64;j++) acc += p_s[64+j] * lfreg[j];
      aput(&ctxp[((size_t)b_att*NTS + ts)*Dn + tid], acc);
    }
    gbarE(eline);

    // ================= C phase =================
    if(tid < NTS){
      red_s[16+tid] = mst[(size_t)b_att*NTS + tid];
      red_s[24+tid] = lst[(size_t)b_att*NTS + tid];
    }
    __syncthreads();
    if(tid == 0){
      float m = -3.0e38f;
#pragma unroll
      for(int j=0;j<NTS;j++) m = fmaxf(m, red_s[16+j]);
      float l = 0.f;
#pragma unroll
      for(int j=0;j<NTS;j++){ float fac = expf(red_s[16+j]-m); red_s[j]=fac; l += fac*red_s[24+j]; }
      red_s[8]=m; red_s[9]=l;
    }
    __syncthreads();
    {
      const float gm = red_s[8];
      const float gl = red_s[9];
      if(tid < TT)
        out[OUT_ATT + ((size_t)s*Bn + b_att)*Tn + (size_t)ts*TT + tid] = expf(e_s[tid] - gm)/gl;
      if(tid < 64){
        const int d = ts*64 + tid;
        float acc = 0.f;
#pragma unroll
        for(int j=0;j<NTS;j++) acc += red_s[j] * ctxp[((size_t)b_att*NTS + j)*Dn + d];
        const float cv = acc / gl;
        ctxc_s[tid] = cv;
        aput(&xctx[(size_t)b_att*Dn + d], cv);
      }
    }
    __syncthreads();
    {  // logits partial over this block's K chunk
      const int v = tid>>3, q = tid&7;
      const float4* hp = (const float4*)(h_s + ts*64 + q*8);
      const float4* cp = (const float4*)(ctxc_s + q*8);
      float4 ha = hp[0], hb = hp[1], ca = cp[0], cb = cp[1];
      float acc = oh0.x*ha.x + oh0.y*ha.y + oh0.z*ha.z + oh0.w*ha.w
                + oh1.x*hb.x + oh1.y*hb.y + oh1.z*hb.z + oh1.w*hb.w
                + oc0.x*ca.x + oc0.y*ca.y + oc0.z*ca.z + oc0.w*ca.w
                + oc1.x*cb.x + oc1.y*cb.y + oc1.z*cb.z + oc1.w*cb.w;
#pragma unroll
      for(int off=1; off<8; off<<=1) acc += __shfl_xor(acc, off);
      if(q == 0) aput(&lgp[((size_t)b_att*Vn + v)*8 + ts], acc);
    }
    gbar2(wsu, ++gg);
  }
}

// ============================================================================
// bf16-input fallback: round-1 structure (passed), per-batch barrier groups.
// ============================================================================
__device__ __forceinline__ void gbar8(unsigned int* bar){
  asm volatile("s_waitcnt vmcnt(0)" ::: "memory");
  __syncthreads();
  if(threadIdx.x==0){
    unsigned int g = uget(bar+1);
    unsigned int p = __hip_atomic_fetch_add(bar, 1u, __ATOMIC_RELAXED, __HIP_MEMORY_SCOPE_AGENT);
    if(p == g*NTS + (NTS-1)){
      __hip_atomic_store(bar+1, g+1u, __ATOMIC_RELAXED, __HIP_MEMORY_SCOPE_AGENT);
    } else {
      while(uget(bar+1) == g) __builtin_amdgcn_s_sleep(2);
    }
  }
  __syncthreads();
  asm volatile("" ::: "memory");
}

__global__ __launch_bounds__(NTHREADS, 2)
void speller_bf16(const unsigned short* __restrict__ lf, const unsigned short* __restrict__ wih,
                  const unsigned short* __restrict__ whh, const unsigned short* __restrict__ bih,
                  const unsigned short* __restrict__ bhh, const unsigned short* __restrict__ wout,
                  const unsigned short* __restrict__ bout, unsigned short* __restrict__ out,
                  float* __restrict__ ws)
{
  { unsigned int fl = __hip_atomic_load((unsigned int*)ws + 512, __ATOMIC_ACQUIRE, __HIP_MEMORY_SCOPE_AGENT);
    if(fl != 1u) return; }
  const int tid = threadIdx.x;
  const int b   = (int)(blockIdx.x >> 3);
  const int ts  = (int)(blockIdx.x & 7);

  extern __shared__ char smem[];
  unsigned short* lf_s = (unsigned short*)smem;           // [128][512] bf16
  float* h_s   = (float*)(smem + 131072);
  float* ctx_s = h_s + 512;
  float* e_s   = ctx_s + 512;
  float* p_s   = e_s + 128;
  float* lg_s  = p_s + 128;
  float* red_s = lg_s + 64;
  float* c_s   = red_s + 32;
  int*   i_s   = (int*)(c_s + 64);

  unsigned int* bar = (unsigned int*)ws + (size_t)b*16 + 4;
  float* hbuf = ws + 1024  + (size_t)b*Hn;
  float* mstB = ws + WS_MST + (size_t)b*NTS;
  float* lstB = ws + WS_LST + (size_t)b*NTS;
  float* ctxpB= ws + WS_CTXP + (size_t)b*NTS*Dn;

  {
    const uint4* s4 = (const uint4*)(lf + ((size_t)b*Tn + (size_t)ts*TT) * Dn);
    uint4* d4 = (uint4*)lf_s;
#pragma unroll
    for(int i=0;i<16;i++) d4[tid + i*NTHREADS] = s4[tid + i*NTHREADS];
  }
  h_s[tid] = 0.f;
  if(tid < 64) c_s[tid] = 0.f;
  if(tid == 0) i_s[0] = 0;
  __syncthreads();

  for(int s = 0; s <= Sn; ++s){
    if(s > 0){
      if(tid < NTS){ red_s[16+tid] = aget(&mstB[tid]); red_s[24+tid] = aget(&lstB[tid]); }
      __syncthreads();
      if(tid == 0){
        float m = -3.0e38f;
#pragma unroll
        for(int j=0;j<NTS;j++) m = fmaxf(m, red_s[16+j]);
        float l = 0.f;
#pragma unroll
        for(int j=0;j<NTS;j++){ float fac = expf(red_s[16+j]-m); red_s[j]=fac; l += fac*red_s[24+j]; }
        red_s[8]=m; red_s[9]=l;
      }
      __syncthreads();
      const float gm = red_s[8];
      const float gl = red_s[9];
      {
        float acc = 0.f;
#pragma unroll
        for(int j=0;j<NTS;j++) acc += red_s[j] * aget(&ctxpB[(size_t)j*Dn + tid]);
        ctx_s[tid] = acc / gl;
      }
      if(tid < TT)
        out[OUT_ATT + ((size_t)(s-1)*Bn + b)*Tn + (size_t)ts*TT + tid] = f2bf(expf(e_s[tid]-gm)/gl);
      __syncthreads();
      {
        const int j = tid >> 3, ks = tid & 7;
        const unsigned short* wr = wout + (size_t)j*(2*Hn) + ks*128;
        float acc;
        if(ks < 4) acc = dot64g(wr, h_s + ks*128)       + dot64g(wr+64, h_s + ks*128 + 64);
        else       acc = dot64g(wr, ctx_s + (ks-4)*128) + dot64g(wr+64, ctx_s + (ks-4)*128 + 64);
#pragma unroll
        for(int off=1; off<8; off<<=1) acc += __shfl_xor(acc, off);
        if(ks==0) lg_s[j] = acc + bfu(bout[j]);
      }
      __syncthreads();
      if(tid < Vn){
        const float lv = lg_s[tid];
        float mv = lv; int mi = tid;
#pragma unroll
        for(int off=1; off<64; off<<=1){
          float ov = __shfl_xor(mv, off);
          int   oi = __shfl_xor(mi, off);
          if(ov > mv || (ov == mv && oi < mi)){ mv = ov; mi = oi; }
        }
        float se = expf(lv - mv);
#pragma unroll
        for(int off=1; off<64; off<<=1) se += __shfl_xor(se, off);
        if(ts == 0) out[((size_t)(s-1)*Bn + b)*Vn + tid] = f2bf(lv - mv - logf(se));
        if(tid == 0) i_s[0] = mi;
      }
      __syncthreads();
    } else {
      ctx_s[tid] = bfu(lf[(size_t)b*Tn*Dn + tid]);
      __syncthreads();
    }

    if(s == Sn) break;

    {
      const int u  = tid >> 3;
      const int ks = tid & 7;
      const int uu = ts*64 + u;
      const unsigned short* wi0 = wih + (size_t)(       uu)*KIH + 64 + ks*64;
      const unsigned short* wi1 = wih + (size_t)(  Hn + uu)*KIH + 64 + ks*64;
      const unsigned short* wi2 = wih + (size_t)(2*Hn + uu)*KIH + 64 + ks*64;
      const unsigned short* wi3 = wih + (size_t)(3*Hn + uu)*KIH + 64 + ks*64;
      const unsigned short* wh0 = whh + (size_t)(       uu)*Hn + ks*64;
      const unsigned short* wh1 = whh + (size_t)(  Hn + uu)*Hn + ks*64;
      const unsigned short* wh2 = whh + (size_t)(2*Hn + uu)*Hn + ks*64;
      const unsigned short* wh3 = whh + (size_t)(3*Hn + uu)*Hn + ks*64;
      const float4* xc = (const float4*)(ctx_s + ks*64);
      const float4* xh4 = (const float4*)(h_s   + ks*64);
      float a0=0.f,a1=0.f,a2=0.f,a3=0.f;
#pragma unroll
      for(int i=0;i<8;i++){
        float4 p0 = xc[2*i], p1 = xc[2*i+1];
        a0 += dot8(ld8(wi0+8*i), p0, p1);
        a1 += dot8(ld8(wi1+8*i), p0, p1);
        a2 += dot8(ld8(wi2+8*i), p0, p1);
        a3 += dot8(ld8(wi3+8*i), p0, p1);
      }
#pragma unroll
      for(int i=0;i<8;i++){
        float4 p0 = xh4[2*i], p1 = xh4[2*i+1];
        a0 += dot8(ld8(wh0+8*i), p0, p1);
        a1 += dot8(ld8(wh1+8*i), p0, p1);
        a2 += dot8(ld8(wh2+8*i), p0, p1);
        a3 += dot8(ld8(wh3+8*i), p0, p1);
      }
#pragma unroll
      for(int off=1; off<8; off<<=1){
        a0 += __shfl_xor(a0, off);
        a1 += __shfl_xor(a1, off);
        a2 += __shfl_xor(a2, off);
        a3 += __shfl_xor(a3, off);
      }
      if(ks == 0){
        const int pidx = i_s[0];
        const int r0 = uu, r1 = Hn+uu, r2 = 2*Hn+uu, r3 = 3*Hn+uu;
        float gi = a0 + bfu(wih[(size_t)r0*KIH + pidx]) + bfu(bih[r0]) + bfu(bhh[r0]);
        float gf = a1 + bfu(wih[(size_t)r1*KIH + pidx]) + bfu(bih[r1]) + bfu(bhh[r1]);
        float gg = a2 + bfu(wih[(size_t)r2*KIH + pidx]) + bfu(bih[r2]) + bfu(bhh[r2]);
        float go = a3 + bfu(wih[(size_t)r3*KIH + pidx]) + bfu(bih[r3]) + bfu(bhh[r3]);
        gi = sigm(gi); gf = sigm(gf); gg = tnh(gg); go = sigm(go);
        float c = gf*c_s[u] + gi*gg;
        c_s[u] = c;
        aput(&hbuf[uu], go * tnh(c));
      }
    }
    gbar8(bar);

    h_s[tid] = aget(&hbuf[tid]);
    __syncthreads();
    {
      const int t2 = tid >> 3;
      const int q  = tid & 7;
      const float4* hq = (const float4*)(h_s + q*64);
      float ea=0.f, eb=0.f;
      const unsigned short* la = lf_s + (size_t)(2*t2  )*Dn + q*64;
      const unsigned short* lb = lf_s + (size_t)(2*t2+1)*Dn + q*64;
#pragma unroll
      for(int i=0;i<8;i++){
        float4 p0 = hq[2*i], p1 = hq[2*i+1];
        ea += dot8(ld8(la+8*i), p0, p1);
        eb += dot8(ld8(lb+8*i), p0, p1);
      }
#pragma unroll
      for(int off=1; off<8; off<<=1){ ea += __shfl_xor(ea,off); eb += __shfl_xor(eb,off); }
      if(q==0){ e_s[2*t2] = ea; e_s[2*t2+1] = eb; }
    }
    __syncthreads();
    if(tid < 64){
      float v = fmaxf(e_s[tid], e_s[tid+64]);
#pragma unroll
      for(int off=1; off<64; off<<=1) v = fmaxf(v, __shfl_xor(v,off));
      if(tid==0) red_s[10] = v;
    }
    __syncthreads();
    if(tid < TT) p_s[tid] = expf(e_s[tid] - red_s[10]);
    __syncthreads();
    if(tid < 64){
      float v = p_s[tid] + p_s[tid+64];
#pragma unroll
      for(int off=1; off<64; off<<=1) v += __shfl_xor(v,off);
      if(tid==0){ aput(&mstB[ts], red_s[10]); aput(&lstB[ts], v); }
    }
    {
      float acc = 0.f;
      const unsigned short* col = lf_s + tid;
#pragma unroll 4
      for(int t=0;t<TT;t++) acc += p_s[t] * bfu(col[(size_t)t*Dn]);
      aput(&ctxpB[(size_t)ts*Dn + tid], acc);
    }
    gbar8(bar);
  }
}

extern "C" void kernel_launch(void* const* d_in, const int* in_sizes, int n_in,
                              void* d_out, int out_size, void* d_ws, size_t ws_size,
                              hipStream_t stream) {
  (void)in_sizes; (void)n_in; (void)out_size; (void)ws_size;
  float* ws = (float*)d_ws;

  hipFuncSetAttribute(reinterpret_cast<const void*>(&speller_v3),
                      hipFuncAttributeMaxDynamicSharedMemorySize, LDS_BYTES);
  hipFuncSetAttribute(reinterpret_cast<const void*>(&speller_bf16),
                      hipFuncAttributeMaxDynamicSharedMemorySize, LDS_BYTES);
  // barriers + flags live in the first 4 KB (d_ws is poisoned before every launch)
  hipMemsetAsync(d_ws, 0, 4096, stream);
  dtype_probe<<<dim3(1), dim3(64), 0, stream>>>((const unsigned short*)d_in[3],
                                                (unsigned int*)d_ws + 512);
  speller_v3<<<dim3(NBLK), dim3(NTHREADS), LDS_BYTES, stream>>>(
      (const float*)d_in[0], (const float*)d_in[1], (const float*)d_in[2],
      (const float*)d_in[3], (const float*)d_in[4], (const float*)d_in[5],
      (const float*)d_in[6], (float*)d_out, ws);
  speller_bf16<<<dim3(NBLK), dim3(NTHREADS), LDS_BYTES, stream>>>(
      (const unsigned short*)d_in[0], (const unsigned short*)d_in[1],
      (const unsigned short*)d_in[2], (const unsigned short*)d_in[3],
      (const unsigned short*)d_in[4], (const unsigned short*)d_in[5],
      (const unsigned short*)d_in[6], (unsigned short*)d_out, ws);
}

// Round 8
// 6851.496 us; speedup vs baseline: 1.0390x; 1.0390x over previous
//
#include <hip/hip_runtime.h>

// Problem constants
#define Bn 32
#define Tn 1024
#define Dn 512
#define Hn 512
#define Vn 64
#define Sn 128
#define NTS 8          // t-slices per batch
#define TT 128         // T per block (attention role)
#define NTHREADS 512
#define KIH 576        // W_ih cols (V + H)
#define NBLK 256

// LDS: 131072 (tile) + 9248 (scratch) = 140320 -> 143360 (1 blk/CU)
#define LDS_BYTES 143360
#define OUT_ATT ((size_t)Sn * Bn * Vn)

// ws u32-index layout, first 4KB (memset to 0 each launch):
//   [g*16 + 0]  : global-barrier arrival counter for group g (monotonic)
//   [g*16 + 4,5]: E->C group barrier (arrivals, gen) for group g
//   [512]       : dtype flag (probe)
// ws float-index layout:
#define WS_XCTX  1024     // [32][512]  ctx(s-1)
#define WS_XH    17408    // [2][32][512] h double-buffered by step parity
#define WS_LGP   50176    // [32][64][8] logits partials
#define WS_MST   66560    // [32][8]
#define WS_LST   66816    // [32][8]
#define WS_CTXP  67072    // [32][8][512]

struct F8 { float4 a, b; };

__device__ __forceinline__ float bfu(unsigned short u){ return __uint_as_float(((unsigned int)u)<<16); }
__device__ __forceinline__ float bflo(unsigned int u){ return __uint_as_float(u<<16); }
__device__ __forceinline__ float bfhi(unsigned int u){ return __uint_as_float(u & 0xffff0000u); }
__device__ __forceinline__ unsigned short f2bf(float f){
  unsigned int x = __float_as_uint(f);
  return (unsigned short)((x + 0x7fffu + ((x>>16)&1u)) >> 16);   // RNE
}
__device__ __forceinline__ F8 ld8(const unsigned short* p){
  uint4 q = *(const uint4*)p;
  F8 r;
  r.a = make_float4(bflo(q.x), bfhi(q.x), bflo(q.y), bfhi(q.y));
  r.b = make_float4(bflo(q.z), bfhi(q.z), bflo(q.w), bfhi(q.w));
  return r;
}
__device__ __forceinline__ F8 ld8(const float* p){
  F8 r; r.a = *(const float4*)p; r.b = *(const float4*)(p+4); return r;
}
__device__ __forceinline__ float dot8(F8 w, float4 a, float4 b){
  return w.a.x*a.x + w.a.y*a.y + w.a.z*a.z + w.a.w*a.w
       + w.b.x*b.x + w.b.y*b.y + w.b.z*b.z + w.b.w*b.w;
}
__device__ __forceinline__ float dot64g(const unsigned short* __restrict__ w, const float* x){
  const float4* x4 = (const float4*)x;
  float acc = 0.f;
#pragma unroll
  for(int i=0;i<8;i++) acc += dot8(ld8(w+8*i), x4[2*i], x4[2*i+1]);
  return acc;
}
__device__ __forceinline__ float sigm(float x){
  x = fminf(fmaxf(x, -30.f), 30.f); return 1.f/(1.f + expf(-x));
}
__device__ __forceinline__ float tnh(float x){
  return tanhf(fminf(fmaxf(x, -20.f), 20.f));
}

// Recursive-halving reduce-scatter (R6-verified): after rs32, lane pair
// {2i,2i+1} holds in a[0] the 64-lane sum of value index i (i in 0..31).
template<int N>
__device__ __forceinline__ void rs_round(float* a, int off, bool hi){
#pragma unroll
  for(int i=0;i<N;i++){
    float send = hi ? a[i]   : a[i+N];
    float keep = hi ? a[i+N] : a[i];
    float recv = __shfl_xor(send, off);
    a[i] = keep + recv;
  }
}
__device__ __forceinline__ void rs32(float* a, int lane){
  rs_round<16>(a, 32, (lane&32)!=0);
  rs_round< 8>(a, 16, (lane&16)!=0);
  rs_round< 4>(a,  8, (lane& 8)!=0);
  rs_round< 2>(a,  4, (lane& 4)!=0);
  rs_round< 1>(a,  2, (lane& 2)!=0);
  a[0] += __shfl_xor(a[0], 1);
}

// ---- relaxed agent-scope atomics (LLC-direct; bypass stale L1/L2) ----
__device__ __forceinline__ void aput(float* p, float v){
  __hip_atomic_store(p, v, __ATOMIC_RELAXED, __HIP_MEMORY_SCOPE_AGENT);
}
__device__ __forceinline__ float aget(const float* p){
  return __hip_atomic_load(p, __ATOMIC_RELAXED, __HIP_MEMORY_SCOPE_AGENT);
}
__device__ __forceinline__ unsigned int uget(const unsigned int* p){
  return __hip_atomic_load(p, __ATOMIC_RELAXED, __HIP_MEMORY_SCOPE_AGENT);
}

// ---- all-poll global barrier (R7-proven) ----
// Arrivals distributed over 32 group lines (8 RMWs each, parallel). Every
// block's wave 0 gather-polls all 32 counters (reads only). ACQ: one ACQUIRE
// load at exit (L1/L2 invalidate) — only where subsequent PLAIN vectorized
// loads need coherence (G's lgp reads, gates' x reads). Acquire-free exits
// are paired with aget (LLC-direct) reads instead.
template<bool ACQ>
__device__ __forceinline__ void gbar2(unsigned int* wsu, unsigned int ggen){
  asm volatile("s_waitcnt vmcnt(0)" ::: "memory");
  __syncthreads();
  const int tid = threadIdx.x;
  const int grp = (int)blockIdx.x >> 3;
  if(tid == 0)
    __hip_atomic_fetch_add(&wsu[grp*16], 1u, __ATOMIC_RELEASE, __HIP_MEMORY_SCOPE_AGENT);
  if(tid < 64){
    const unsigned int tgt = 8u*ggen;
    for(;;){
      unsigned int v = (tid < 32) ? uget(&wsu[tid*16]) : tgt;
      if(__all(v >= tgt)) break;
      __builtin_amdgcn_s_sleep(1);
    }
    if(ACQ && tid == 0){
      unsigned int x = __hip_atomic_load(&wsu[grp*16], __ATOMIC_ACQUIRE, __HIP_MEMORY_SCOPE_AGENT);
      asm volatile("" :: "v"(x));
    }
  }
  __syncthreads();
  asm volatile("" ::: "memory");
}

// ---- 8-block group barrier (E->C; partials group-local, read via aget) ----
__device__ __forceinline__ void gbarE(unsigned int* line){
  asm volatile("s_waitcnt vmcnt(0)" ::: "memory");
  __syncthreads();
  if(threadIdx.x == 0){
    unsigned int g = uget(line+1);
    unsigned int p = __hip_atomic_fetch_add(line, 1u, __ATOMIC_RELEASE, __HIP_MEMORY_SCOPE_AGENT);
    if(p == g*8u + 7u){
      __hip_atomic_store(line+1, g+1u, __ATOMIC_RELEASE, __HIP_MEMORY_SCOPE_AGENT);
    } else {
      while(uget(line+1) == g) __builtin_amdgcn_s_sleep(1);
    }
  }
  __syncthreads();
  asm volatile("" ::: "memory");
}

// dtype probe: b_ih ~ N(0,0.01^2). flag: 1 = bf16, 2 = f32.
__global__ void dtype_probe(const unsigned short* __restrict__ b3, unsigned int* flag){
  const int t = threadIdx.x;
  bool ok = true;
#pragma unroll
  for(int i=0;i<8;i++){
    float v = bfu(b3[2*(t*8+i)]);
    ok = ok && (v == v) && (fabsf(v) < 0.5f);
  }
  unsigned long long m = __ballot(ok);
  if(t == 0)
    __hip_atomic_store(flag, (m == ~0ull) ? 1u : 2u, __ATOMIC_RELEASE, __HIP_MEMORY_SCOPE_AGENT);
}

// ============================================================================
// v8 (f32 inputs): R6 compute structure (weights on-chip, 2 units x 32 batches
// gates, rs32 reductions) + R7 all-poll barrier + invalidate-minimization:
// only the end-of-C barrier ACQUIREs; E and C read cross-block data via aget.
// ============================================================================
__global__ __launch_bounds__(NTHREADS, 1)
void speller_v3(const float* __restrict__ lf,  const float* __restrict__ wih,
                const float* __restrict__ whh, const float* __restrict__ bih,
                const float* __restrict__ bhh, const float* __restrict__ wout,
                const float* __restrict__ bout, float* __restrict__ out,
                float* __restrict__ ws)
{
  { unsigned int fl = __hip_atomic_load((unsigned int*)ws + 512, __ATOMIC_ACQUIRE, __HIP_MEMORY_SCOPE_AGENT);
    if(fl != 2u) return; }

  const int tid   = threadIdx.x;
  const int UP    = (int)blockIdx.x;      // unit-pair id; units 2UP, 2UP+1
  const int b_att = UP >> 3;              // attention batch
  const int ts    = UP & 7;               // attention t-slice
  const int w     = tid >> 6;             // wave 0..7
  const int lane  = tid & 63;

  extern __shared__ char smem[];
  float* tile   = (float*)smem;                 // [64][512] f32 swizzled LF rows 0..63
  float* epart  = (float*)(smem + 131072);      // [512]
  float* h_s    = epart + 512;                  // [512]
  float* e_s    = h_s + 512;                    // [128]
  float* p_s    = e_s + 128;                    // [128]
  float* red_s  = p_s + 128;                    // [32]
  float* pre_s  = red_s + 32;                   // [8][32] gate pre-activations
  float* ctxc_s = pre_s + 256;                  // [64]
  float* c_s    = ctxc_s + 64;                  // [64] cell state (bb*2+ul)
  float* bias_s = c_s + 64;                     // [8]
  float* bout_s = bias_s + 8;                   // [64]
  int*   pall_s = (int*)(bout_s + 64);          // [32] argmax per batch
  float* wow_s  = (float*)(pall_s + 32);        // [8][64] W_ih one-hot cols
  // end of scratch = 131072 + 9248 = 140320 <= LDS_BYTES

  unsigned int* wsu   = (unsigned int*)ws;
  unsigned int* eline = wsu + (size_t)b_att*16 + 4;
  float* xctx = ws + WS_XCTX;
  float* xh   = ws + WS_XH;
  float* lgp  = ws + WS_LGP;
  float* mst  = ws + WS_MST;
  float* lst  = ws + WS_LST;
  float* ctxp = ws + WS_CTXP;

  // this wave's gate-row: g = w>>1, unit = 2UP + (w&1)
  const int rw = (w>>1)*Hn + 2*UP + (w&1);

  // ---- persistent weight registers ----
  float4 wv0, wv1, wv2, wv3;      // 16-float gate-row chunk
  {
    const int k0 = 16*lane;
    const float* wp = (lane < 32) ? (wih + (size_t)rw*KIH + 64 + k0)
                                  : (whh + (size_t)rw*Hn + (k0 - 512));
    wv0 = *(const float4*)wp;     wv1 = *(const float4*)(wp+4);
    wv2 = *(const float4*)(wp+8); wv3 = *(const float4*)(wp+12);
  }
  float4 oh0, oh1, oc0, oc1;      // W_out K-slice: h-cols and ctx-cols
  {
    const int v = tid>>3, q = tid&7;
    const float* pH = wout + (size_t)v*(2*Hn) + ts*64 + q*8;
    const float* pC = pH + Hn;
    oh0 = *(const float4*)pH; oh1 = *(const float4*)(pH+4);
    oc0 = *(const float4*)pC; oc1 = *(const float4*)(pC+4);
  }

  // ---- LDS weight/aux fills ----
  {
    const int rr = tid>>6, cc = tid&63;
    const int r2 = (rr>>1)*Hn + 2*UP + (rr&1);
    wow_s[tid] = wih[(size_t)r2*KIH + cc];
  }
  if(tid < 8){ const int r2 = (tid>>1)*Hn + 2*UP + (tid&1); bias_s[tid] = bih[r2] + bhh[r2]; }
  if(tid < Vn) bout_s[tid] = bout[tid];
  if(tid < 64) c_s[tid] = 0.f;
  if(tid < 32) pall_s[tid] = 0;

  // ---- LF staging: rows 0..63 -> swizzled LDS; rows 64..127 -> registers ----
  float lfreg[64];
  {
    const float4* s4 = (const float4*)(lf + ((size_t)b_att*Tn + (size_t)ts*TT) * Dn);
    float4* d4 = (float4*)tile;
#pragma unroll
    for(int i=0;i<16;i++){
      const int f = tid + i*NTHREADS;       // float4 index in [0,8192)
      const int row = f >> 7, cc = f & 127;
      d4[(row << 7) | (cc ^ (row & 7))] = s4[f];
    }
    const float* lfg = lf + ((size_t)b_att*Tn + (size_t)ts*TT + 64) * Dn + tid;
#pragma unroll
    for(int j=0;j<64;j++) lfreg[j] = lfg[(size_t)j*Dn];
  }

  // ---- ws init: ctx(-1) = LF[:,0,:]; h(-1) = 0 (parity buffer 1) ----
  if(tid < 64){
    aput(&xctx[(size_t)b_att*Dn + ts*64 + tid], lf[(size_t)b_att*Tn*Dn + ts*64 + tid]);
    const int bb = tid>>1, ul = tid&1;
    aput(&xh[(size_t)Bn*Hn + (size_t)bb*Hn + 2*UP + ul], 0.f);
  }
  __syncthreads();
  unsigned int gg = 0;
  gbar2<true>(wsu, ++gg);

  for(int s = 0; s <= Sn; ++s){
    // ================= G phase =================
    if(s > 0){   // logits(s-1) assembly + argmax (all blocks) + logp (writer blocks)
      for(int ii=0; ii<4; ++ii){
        const int bb = 4*w + ii;
        float lv = bout_s[lane];
        const float4* lp = (const float4*)(lgp + ((size_t)bb*Vn + lane)*8);
        float4 qa = lp[0], qb = lp[1];
        lv += qa.x+qa.y+qa.z+qa.w + qb.x+qb.y+qb.z+qb.w;
        float mv = lv; int mi = lane;
#pragma unroll
        for(int off=1; off<64; off<<=1){
          float ov = __shfl_xor(mv, off);
          int   oi = __shfl_xor(mi, off);
          if(ov > mv || (ov == mv && oi < mi)){ mv = ov; mi = oi; }
        }
        float se = expf(lv - mv);
#pragma unroll
        for(int off=1; off<64; off<<=1) se += __shfl_xor(se, off);
        if(lane == 0) pall_s[bb] = mi;
        if(UP == 8*bb) out[((size_t)(s-1)*Bn + bb)*Vn + lane] = lv - mv - logf(se);
      }
    }
    if(s == Sn) break;
    __syncthreads();   // pall_s ready

    // gates GEMV: wave = row, lane = 16-dim K chunk; FMA accumulate + rs32.
    {
      const float* xhR = xh + (size_t)(((s+1)&1))*Bn*Hn;   // h(s-1)
      const int k0 = 16*lane;
      const float* xbase = (lane < 32) ? (xctx + k0) : (xhR + (k0 - 512));
      float acc[Bn];
#pragma unroll
      for(int bb=0; bb<Bn; ++bb){
        const float4* xp = (const float4*)(xbase + (size_t)bb*Dn);
        float4 x0 = xp[0], x1 = xp[1], x2 = xp[2], x3 = xp[3];
        acc[bb] = wv0.x*x0.x + wv0.y*x0.y + wv0.z*x0.z + wv0.w*x0.w
                + wv1.x*x1.x + wv1.y*x1.y + wv1.z*x1.z + wv1.w*x1.w
                + wv2.x*x2.x + wv2.y*x2.y + wv2.z*x2.z + wv2.w*x2.w
                + wv3.x*x3.x + wv3.y*x3.y + wv3.z*x3.z + wv3.w*x3.w;
      }
      rs32(acc, lane);
      if((lane & 1) == 0) pre_s[w*Bn + (lane>>1)] = acc[0];
    }
    __syncthreads();
    if(tid < 64){   // c,h update: 2 units x 32 batches
      const int bb = tid>>1, ul = tid&1;
      const int pidx = pall_s[bb];
      float gi = sigm(pre_s[(0+ul)*Bn+bb] + wow_s[(0+ul)*64+pidx] + bias_s[0+ul]);
      float gf = sigm(pre_s[(2+ul)*Bn+bb] + wow_s[(2+ul)*64+pidx] + bias_s[2+ul]);
      float gg2 = tnh(pre_s[(4+ul)*Bn+bb] + wow_s[(4+ul)*64+pidx] + bias_s[4+ul]);
      float go = sigm(pre_s[(6+ul)*Bn+bb] + wow_s[(6+ul)*64+pidx] + bias_s[6+ul]);
      float c = gf*c_s[tid] + gi*gg2;
      c_s[tid] = c;
      aput(&xh[(size_t)(s&1)*Bn*Hn + (size_t)bb*Hn + 2*UP + ul], go*tnh(c));
    }
    gbar2<false>(wsu, ++gg);   // E reads xh via aget -> no invalidate needed

    // ================= E phase (attention) =================
    h_s[tid] = aget(&xh[(size_t)(s&1)*Bn*Hn + (size_t)b_att*Hn + tid]);
    __syncthreads();
    {  // rows 0..63: one row per thread-group from swizzled tile
      const int t1 = tid >> 3, q = tid & 7, mm = t1 & 7;
      const float4* lrow = (const float4*)tile + (size_t)t1*128;
      const float4* hq = (const float4*)(h_s + q*64);
      float ea = 0.f;
#pragma unroll
      for(int i=0;i<8;i++){
        const int c0 = q*16 + 2*i;
        F8 wv; wv.a = lrow[c0 ^ mm]; wv.b = lrow[(c0+1) ^ mm];
        ea += dot8(wv, hq[2*i], hq[2*i+1]);
      }
#pragma unroll
      for(int off=1; off<8; off<<=1) ea += __shfl_xor(ea, off);
      if(q==0) e_s[t1] = ea;
    }
    {  // rows 64..127: reduce-scatter over register columns, two 32-row halves
      const float h_own = h_s[tid];
      float a[32];
#pragma unroll
      for(int j=0;j<32;j++) a[j] = h_own * lfreg[j];
      rs32(a, lane);
      if((lane & 1) == 0) epart[(w<<6) + (lane>>1)] = a[0];
#pragma unroll
      for(int j=0;j<32;j++) a[j] = h_own * lfreg[32+j];
      rs32(a, lane);
      if((lane & 1) == 0) epart[(w<<6) + 32 + (lane>>1)] = a[0];
    }
    __syncthreads();
    if(tid < 64){
      float s2 = 0.f;
#pragma unroll
      for(int w2=0; w2<8; w2++) s2 += epart[(w2<<6) + tid];
      e_s[64 + tid] = s2;
      float v = fmaxf(e_s[tid], s2);
#pragma unroll
      for(int off=1; off<64; off<<=1) v = fmaxf(v, __shfl_xor(v,off));
      if(tid==0) red_s[10] = v;
    }
    __syncthreads();
    if(tid < TT) p_s[tid] = expf(e_s[tid] - red_s[10]);
    __syncthreads();
    if(tid < 64){
      float v = p_s[tid] + p_s[tid+64];
#pragma unroll
      for(int off=1; off<64; off<<=1) v += __shfl_xor(v,off);
      if(tid==0){
        aput(&mst[(size_t)b_att*NTS + ts], red_s[10]);
        aput(&lst[(size_t)b_att*NTS + ts], v);
      }
    }
    {  // ctx partial: thread owns one d, sweep 128 t's
      float acc = 0.f;
      const int cs = tid >> 2, cr = tid & 3;
#pragma unroll
      for(int t=0;t<64;t++)
        acc += p_s[t] * tile[(size_t)t*Dn + (((cs ^ (t&7))<<2) | cr)];
#pragma unroll
      for(int j=0;j<64;j++) acc += p_s[64+j] * lfreg[j];
      aput(&ctxp[((size_t)b_att*NTS + ts)*Dn + tid], acc);
    }
    gbarE(eline);   // C reads mst/lst/ctxp via aget -> no invalidate needed

    // ================= C phase =================
    if(tid < NTS){
      red_s[16+tid] = aget(&mst[(size_t)b_att*NTS + tid]);
      red_s[24+tid] = aget(&lst[(size_t)b_att*NTS + tid]);
    }
    __syncthreads();
    if(tid == 0){
      float m = -3.0e38f;
#pragma unroll
      for(int j=0;j<NTS;j++) m = fmaxf(m, red_s[16+j]);
      float l = 0.f;
#pragma unroll
      for(int j=0;j<NTS;j++){ float fac = expf(red_s[16+j]-m); red_s[j]=fac; l += fac*red_s[24+j]; }
      red_s[8]=m; red_s[9]=l;
    }
    __syncthreads();
    {
      const float gm = red_s[8];
      const float gl = red_s[9];
      if(tid < TT)
        out[OUT_ATT + ((size_t)s*Bn + b_att)*Tn + (size_t)ts*TT + tid] = expf(e_s[tid] - gm)/gl;
      if(tid < 64){
        const int d = ts*64 + tid;
        float acc = 0.f;
#pragma unroll
        for(int j=0;j<NTS;j++) acc += red_s[j] * aget(&ctxp[((size_t)b_att*NTS + j)*Dn + d]);
        const float cv = acc / gl;
        ctxc_s[tid] = cv;
        aput(&xctx[(size_t)b_att*Dn + d], cv);
      }
    }
    __syncthreads();
    {  // logits partial over this block's K chunk
      const int v = tid>>3, q = tid&7;
      const float4* hp = (const float4*)(h_s + ts*64 + q*8);
      const float4* cp = (const float4*)(ctxc_s + q*8);
      float4 ha = hp[0], hb = hp[1], ca = cp[0], cb = cp[1];
      float acc = oh0.x*ha.x + oh0.y*ha.y + oh0.z*ha.z + oh0.w*ha.w
                + oh1.x*hb.x + oh1.y*hb.y + oh1.z*hb.z + oh1.w*hb.w
                + oc0.x*ca.x + oc0.y*ca.y + oc0.z*ca.z + oc0.w*ca.w
                + oc1.x*cb.x + oc1.y*cb.y + oc1.z*cb.z + oc1.w*cb.w;
#pragma unroll
      for(int off=1; off<8; off<<=1) acc += __shfl_xor(acc, off);
      if(q == 0) aput(&lgp[((size_t)b_att*Vn + v)*8 + ts], acc);
    }
    gbar2<true>(wsu, ++gg);   // G/gates use plain vectorized loads -> ACQUIRE
  }
}

// ============================================================================
// bf16-input fallback: round-1 structure (passed), per-batch barrier groups.
// ============================================================================
__device__ __forceinline__ void gbar8(unsigned int* bar){
  asm volatile("s_waitcnt vmcnt(0)" ::: "memory");
  __syncthreads();
  if(threadIdx.x==0){
    unsigned int g = uget(bar+1);
    unsigned int p = __hip_atomic_fetch_add(bar, 1u, __ATOMIC_RELAXED, __HIP_MEMORY_SCOPE_AGENT);
    if(p == g*NTS + (NTS-1)){
      __hip_atomic_store(bar+1, g+1u, __ATOMIC_RELAXED, __HIP_MEMORY_SCOPE_AGENT);
    } else {
      while(uget(bar+1) == g) __builtin_amdgcn_s_sleep(2);
    }
  }
  __syncthreads();
  asm volatile("" ::: "memory");
}

__global__ __launch_bounds__(NTHREADS, 2)
void speller_bf16(const unsigned short* __restrict__ lf, const unsigned short* __restrict__ wih,
                  const unsigned short* __restrict__ whh, const unsigned short* __restrict__ bih,
                  const unsigned short* __restrict__ bhh, const unsigned short* __restrict__ wout,
                  const unsigned short* __restrict__ bout, unsigned short* __restrict__ out,
                  float* __restrict__ ws)
{
  { unsigned int fl = __hip_atomic_load((unsigned int*)ws + 512, __ATOMIC_ACQUIRE, __HIP_MEMORY_SCOPE_AGENT);
    if(fl != 1u) return; }
  const int tid = threadIdx.x;
  const int b   = (int)(blockIdx.x >> 3);
  const int ts  = (int)(blockIdx.x & 7);

  extern __shared__ char smem[];
  unsigned short* lf_s = (unsigned short*)smem;           // [128][512] bf16
  float* h_s   = (float*)(smem + 131072);
  float* ctx_s = h_s + 512;
  float* e_s   = ctx_s + 512;
  float* p_s   = e_s + 128;
  float* lg_s  = p_s + 128;
  float* red_s = lg_s + 64;
  float* c_s   = red_s + 32;
  int*   i_s   = (int*)(c_s + 64);

  unsigned int* bar = (unsigned int*)ws + (size_t)b*16 + 4;
  float* hbuf = ws + 1024  + (size_t)b*Hn;
  float* mstB = ws + WS_MST + (size_t)b*NTS;
  float* lstB = ws + WS_LST + (size_t)b*NTS;
  float* ctxpB= ws + WS_CTXP + (size_t)b*NTS*Dn;

  {
    const uint4* s4 = (const uint4*)(lf + ((size_t)b*Tn + (size_t)ts*TT) * Dn);
    uint4* d4 = (uint4*)lf_s;
#pragma unroll
    for(int i=0;i<16;i++) d4[tid + i*NTHREADS] = s4[tid + i*NTHREADS];
  }
  h_s[tid] = 0.f;
  if(tid < 64) c_s[tid] = 0.f;
  if(tid == 0) i_s[0] = 0;
  __syncthreads();

  for(int s = 0; s <= Sn; ++s){
    if(s > 0){
      if(tid < NTS){ red_s[16+tid] = aget(&mstB[tid]); red_s[24+tid] = aget(&lstB[tid]); }
      __syncthreads();
      if(tid == 0){
        float m = -3.0e38f;
#pragma unroll
        for(int j=0;j<NTS;j++) m = fmaxf(m, red_s[16+j]);
        float l = 0.f;
#pragma unroll
        for(int j=0;j<NTS;j++){ float fac = expf(red_s[16+j]-m); red_s[j]=fac; l += fac*red_s[24+j]; }
        red_s[8]=m; red_s[9]=l;
      }
      __syncthreads();
      const float gm = red_s[8];
      const float gl = red_s[9];
      {
        float acc = 0.f;
#pragma unroll
        for(int j=0;j<NTS;j++) acc += red_s[j] * aget(&ctxpB[(size_t)j*Dn + tid]);
        ctx_s[tid] = acc / gl;
      }
      if(tid < TT)
        out[OUT_ATT + ((size_t)(s-1)*Bn + b)*Tn + (size_t)ts*TT + tid] = f2bf(expf(e_s[tid]-gm)/gl);
      __syncthreads();
      {
        const int j = tid >> 3, ks = tid & 7;
        const unsigned short* wr = wout + (size_t)j*(2*Hn) + ks*128;
        float acc;
        if(ks < 4) acc = dot64g(wr, h_s + ks*128)       + dot64g(wr+64, h_s + ks*128 + 64);
        else       acc = dot64g(wr, ctx_s + (ks-4)*128) + dot64g(wr+64, ctx_s + (ks-4)*128 + 64);
#pragma unroll
        for(int off=1; off<8; off<<=1) acc += __shfl_xor(acc, off);
        if(ks==0) lg_s[j] = acc + bfu(bout[j]);
      }
      __syncthreads();
      if(tid < Vn){
        const float lv = lg_s[tid];
        float mv = lv; int mi = tid;
#pragma unroll
        for(int off=1; off<64; off<<=1){
          float ov = __shfl_xor(mv, off);
          int   oi = __shfl_xor(mi, off);
          if(ov > mv || (ov == mv && oi < mi)){ mv = ov; mi = oi; }
        }
        float se = expf(lv - mv);
#pragma unroll
        for(int off=1; off<64; off<<=1) se += __shfl_xor(se, off);
        if(ts == 0) out[((size_t)(s-1)*Bn + b)*Vn + tid] = f2bf(lv - mv - logf(se));
        if(tid == 0) i_s[0] = mi;
      }
      __syncthreads();
    } else {
      ctx_s[tid] = bfu(lf[(size_t)b*Tn*Dn + tid]);
      __syncthreads();
    }

    if(s == Sn) break;

    {
      const int u  = tid >> 3;
      const int ks = tid & 7;
      const int uu = ts*64 + u;
      const unsigned short* wi0 = wih + (size_t)(       uu)*KIH + 64 + ks*64;
      const unsigned short* wi1 = wih + (size_t)(  Hn + uu)*KIH + 64 + ks*64;
      const unsigned short* wi2 = wih + (size_t)(2*Hn + uu)*KIH + 64 + ks*64;
      const unsigned short* wi3 = wih + (size_t)(3*Hn + uu)*KIH + 64 + ks*64;
      const unsigned short* wh0 = whh + (size_t)(       uu)*Hn + ks*64;
      const unsigned short* wh1 = whh + (size_t)(  Hn + uu)*Hn + ks*64;
      const unsigned short* wh2 = whh + (size_t)(2*Hn + uu)*Hn + ks*64;
      const unsigned short* wh3 = whh + (size_t)(3*Hn + uu)*Hn + ks*64;
      const float4* xc = (const float4*)(ctx_s + ks*64);
      const float4* xh4 = (const float4*)(h_s   + ks*64);
      float a0=0.f,a1=0.f,a2=0.f,a3=0.f;
#pragma unroll
      for(int i=0;i<8;i++){
        float4 p0 = xc[2*i], p1 = xc[2*i+1];
        a0 += dot8(ld8(wi0+8*i), p0, p1);
        a1 += dot8(ld8(wi1+8*i), p0, p1);
        a2 += dot8(ld8(wi2+8*i), p0, p1);
        a3 += dot8(ld8(wi3+8*i), p0, p1);
      }
#pragma unroll
      for(int i=0;i<8;i++){
        float4 p0 = xh4[2*i], p1 = xh4[2*i+1];
        a0 += dot8(ld8(wh0+8*i), p0, p1);
        a1 += dot8(ld8(wh1+8*i), p0, p1);
        a2 += dot8(ld8(wh2+8*i), p0, p1);
        a3 += dot8(ld8(wh3+8*i), p0, p1);
      }
#pragma unroll
      for(int off=1; off<8; off<<=1){
        a0 += __shfl_xor(a0, off);
        a1 += __shfl_xor(a1, off);
        a2 += __shfl_xor(a2, off);
        a3 += __shfl_xor(a3, off);
      }
      if(ks == 0){
        const int pidx = i_s[0];
        const int r0 = uu, r1 = Hn+uu, r2 = 2*Hn+uu, r3 = 3*Hn+uu;
        float gi = a0 + bfu(wih[(size_t)r0*KIH + pidx]) + bfu(bih[r0]) + bfu(bhh[r0]);
        float gf = a1 + bfu(wih[(size_t)r1*KIH + pidx]) + bfu(bih[r1]) + bfu(bhh[r1]);
        float gg = a2 + bfu(wih[(size_t)r2*KIH + pidx]) + bfu(bih[r2]) + bfu(bhh[r2]);
        float go = a3 + bfu(wih[(size_t)r3*KIH + pidx]) + bfu(bih[r3]) + bfu(bhh[r3]);
        gi = sigm(gi); gf = sigm(gf); gg = tnh(gg); go = sigm(go);
        float c = gf*c_s[u] + gi*gg;
        c_s[u] = c;
        aput(&hbuf[uu], go * tnh(c));
      }
    }
    gbar8(bar);

    h_s[tid] = aget(&hbuf[tid]);
    __syncthreads();
    {
      const int t2 = tid >> 3;
      const int q  = tid & 7;
      const float4* hq = (const float4*)(h_s + q*64);
      float ea=0.f, eb=0.f;
      const unsigned short* la = lf_s + (size_t)(2*t2  )*Dn + q*64;
      const unsigned short* lb = lf_s + (size_t)(2*t2+1)*Dn + q*64;
#pragma unroll
      for(int i=0;i<8;i++){
        float4 p0 = hq[2*i], p1 = hq[2*i+1];
        ea += dot8(ld8(la+8*i), p0, p1);
        eb += dot8(ld8(lb+8*i), p0, p1);
      }
#pragma unroll
      for(int off=1; off<8; off<<=1){ ea += __shfl_xor(ea,off); eb += __shfl_xor(eb,off); }
      if(q==0){ e_s[2*t2] = ea; e_s[2*t2+1] = eb; }
    }
    __syncthreads();
    if(tid < 64){
      float v = fmaxf(e_s[tid], e_s[tid+64]);
#pragma unroll
      for(int off=1; off<64; off<<=1) v = fmaxf(v, __shfl_xor(v,off));
      if(tid==0) red_s[10] = v;
    }
    __syncthreads();
    if(tid < TT) p_s[tid] = expf(e_s[tid] - red_s[10]);
    __syncthreads();
    if(tid < 64){
      float v = p_s[tid] + p_s[tid+64];
#pragma unroll
      for(int off=1; off<64; off<<=1) v += __shfl_xor(v,off);
      if(tid==0){ aput(&mstB[ts], red_s[10]); aput(&lstB[ts], v); }
    }
    {
      float acc = 0.f;
      const unsigned short* col = lf_s + tid;
#pragma unroll 4
      for(int t=0;t<TT;t++) acc += p_s[t] * bfu(col[(size_t)t*Dn]);
      aput(&ctxpB[(size_t)ts*Dn + tid], acc);
    }
    gbar8(bar);
  }
}

extern "C" void kernel_launch(void* const* d_in, const int* in_sizes, int n_in,
                              void* d_out, int out_size, void* d_ws, size_t ws_size,
                              hipStream_t stream) {
  (void)in_sizes; (void)n_in; (void)out_size; (void)ws_size;
  float* ws = (float*)d_ws;

  hipFuncSetAttribute(reinterpret_cast<const void*>(&speller_v3),
                      hipFuncAttributeMaxDynamicSharedMemorySize, LDS_BYTES);
  hipFuncSetAttribute(reinterpret_cast<const void*>(&speller_bf16),
                      hipFuncAttributeMaxDynamicSharedMemorySize, LDS_BYTES);
  // barriers + flags live in the first 4 KB (d_ws is poisoned before every launch)
  hipMemsetAsync(d_ws, 0, 4096, stream);
  dtype_probe<<<dim3(1), dim3(64), 0, stream>>>((const unsigned short*)d_in[3],
                                                (unsigned int*)d_ws + 512);
  speller_v3<<<dim3(NBLK), dim3(NTHREADS), LDS_BYTES, stream>>>(
      (const float*)d_in[0], (const float*)d_in[1], (const float*)d_in[2],
      (const float*)d_in[3], (const float*)d_in[4], (const float*)d_in[5],
      (const float*)d_in[6], (float*)d_out, ws);
  speller_bf16<<<dim3(NBLK), dim3(NTHREADS), LDS_BYTES, stream>>>(
      (const unsigned short*)d_in[0], (const unsigned short*)d_in[1],
      (const unsigned short*)d_in[2], (const unsigned short*)d_in[3],
      (const unsigned short*)d_in[4], (const unsigned short*)d_in[5],
      (const unsigned short*)d_in[6], (unsigned short*)d_out, ws);
}